// Round 1
// baseline (416.030 us; speedup 1.0000x reference)
//
#include <hip/hip_runtime.h>

#define BATCH 2048
#define TLEN  512
#define HID   64   // hidden size

typedef _Float16 f16x2 __attribute__((ext_vector_type(2)));

__device__ __forceinline__ float fdot2(f16x2 a, f16x2 b, float c) {
#if __has_builtin(__builtin_amdgcn_fdot2)
    return __builtin_amdgcn_fdot2(a, b, c, false);   // v_dot2_f32_f16, fp32 accumulate
#else
    return c + (float)a[0] * (float)b[0] + (float)a[1] * (float)b[1];
#endif
}

__device__ __forceinline__ f16x2 mk2(float a, float b) {
    f16x2 r; r[0] = (_Float16)a; r[1] = (_Float16)b; return r;
}

__device__ __forceinline__ float rcp_fast(float x) {
    return __builtin_amdgcn_rcpf(x);
}

__device__ __forceinline__ float sigmoid_fast(float x) {
    // 1/(1+e^-x); e^-x -> inf for very negative x gives rcp(inf)=0: correct limit
    return rcp_fast(1.0f + __expf(-x));
}

__device__ __forceinline__ float tanh_fast(float x) {
    // tanh = 1 - 2/(e^{2x}+1); e^{2x} -> inf gives 1, -> 0 gives -1: correct limits
    return 1.0f - 2.0f * rcp_fast(__expf(2.0f * x) + 1.0f);
}

// One wave (64 lanes) per batch element. Lane j owns hidden unit j and gate
// rows {j, 64+j, 128+j, 192+j} of W_hh (PyTorch gate order i,f,g,o), kept in
// registers as 128 packed-f16 pairs. h is broadcast through wave-private LDS.
__global__ __launch_bounds__(256, 2)
void lstm_kernel(const float* __restrict__ x,
                 const float* __restrict__ W_ih,
                 const float* __restrict__ W_hh,
                 const float* __restrict__ b_ih,
                 const float* __restrict__ b_hh,
                 const float* __restrict__ W_d,
                 const float* __restrict__ b_d,
                 float* __restrict__ out) {
    __shared__ __align__(16) float    xs[4][TLEN];  // per-wave x row (8 KB)
    __shared__ __align__(16) _Float16 hs[4][HID];   // per-wave h broadcast (512 B)

    const int lane = threadIdx.x & 63;
    const int wave = threadIdx.x >> 6;
    const int b    = blockIdx.x * 4 + wave;

    float* xsw = xs[wave];
    _Float16* hsw = hs[wave];

    // ---- load this wave's x row into LDS (coalesced float4) ----
    {
        const float4* xr = reinterpret_cast<const float4*>(x + (size_t)b * TLEN);
        float4* xw = reinterpret_cast<float4*>(xsw);
        xw[lane]      = xr[lane];
        xw[lane + 64] = xr[lane + 64];
    }

    // ---- per-lane gate parameters (fp32) ----
    float wih[4], bias[4];
#pragma unroll
    for (int g = 0; g < 4; ++g) {
        const int r = g * HID + lane;
        wih[g]  = W_ih[r];               // input_size == 1
        bias[g] = b_ih[r] + b_hh[r];
    }

    // ---- W_hh rows -> registers as packed f16 pairs: w[g][p] = (W[r,2p],W[r,2p+1]) ----
    f16x2 w[4][32];
#pragma unroll
    for (int g = 0; g < 4; ++g) {
        const float4* wr = reinterpret_cast<const float4*>(W_hh + (size_t)(g * HID + lane) * HID);
#pragma unroll
        for (int q = 0; q < 16; ++q) {
            float4 v = wr[q];
            w[g][2 * q]     = mk2(v.x, v.y);
            w[g][2 * q + 1] = mk2(v.z, v.w);
        }
    }

    __threadfence_block();  // order x LDS writes before loop reads (wave-internal)

    // ---- recurrence ----
    float hval = 0.0f, cval = 0.0f;
    for (int t = 0; t < TLEN; ++t) {
        // broadcast h through LDS as f16 (wave-private buffer; in-order DS + fence)
        hsw[lane] = (_Float16)hval;
        __threadfence_block();

        const float xt = xsw[t];
        float a0 = fmaf(xt, wih[0], bias[0]);
        float a1 = fmaf(xt, wih[1], bias[1]);
        float a2 = fmaf(xt, wih[2], bias[2]);
        float a3 = fmaf(xt, wih[3], bias[3]);

        const uint4* hp = reinterpret_cast<const uint4*>(hsw);
#pragma unroll
        for (int ck = 0; ck < 8; ++ck) {
            const uint4 hv = hp[ck];  // 8 h values, broadcast read (conflict-free)
            const f16x2 h0 = __builtin_bit_cast(f16x2, hv.x);
            const f16x2 h1 = __builtin_bit_cast(f16x2, hv.y);
            const f16x2 h2 = __builtin_bit_cast(f16x2, hv.z);
            const f16x2 h3 = __builtin_bit_cast(f16x2, hv.w);
            const int p = 4 * ck;
            a0 = fdot2(h0, w[0][p + 0], a0);
            a0 = fdot2(h1, w[0][p + 1], a0);
            a0 = fdot2(h2, w[0][p + 2], a0);
            a0 = fdot2(h3, w[0][p + 3], a0);
            a1 = fdot2(h0, w[1][p + 0], a1);
            a1 = fdot2(h1, w[1][p + 1], a1);
            a1 = fdot2(h2, w[1][p + 2], a1);
            a1 = fdot2(h3, w[1][p + 3], a1);
            a2 = fdot2(h0, w[2][p + 0], a2);
            a2 = fdot2(h1, w[2][p + 1], a2);
            a2 = fdot2(h2, w[2][p + 2], a2);
            a2 = fdot2(h3, w[2][p + 3], a2);
            a3 = fdot2(h0, w[3][p + 0], a3);
            a3 = fdot2(h1, w[3][p + 1], a3);
            a3 = fdot2(h2, w[3][p + 2], a3);
            a3 = fdot2(h3, w[3][p + 3], a3);
        }

        const float gi = sigmoid_fast(a0);
        const float gf = sigmoid_fast(a1);
        const float gg = tanh_fast(a2);
        const float go = sigmoid_fast(a3);
        cval = fmaf(gf, cval, gi * gg);
        hval = go * tanh_fast(cval);
    }

    // ---- out[b] = sum_j h_j * W_d[j] + b_d ----
    float p = hval * W_d[lane];
#pragma unroll
    for (int off = 32; off > 0; off >>= 1)
        p += __shfl_xor(p, off, 64);
    if (lane == 0)
        out[b] = p + b_d[0];
}

extern "C" void kernel_launch(void* const* d_in, const int* in_sizes, int n_in,
                              void* d_out, int out_size, void* d_ws, size_t ws_size,
                              hipStream_t stream) {
    const float* x    = (const float*)d_in[0];
    const float* W_ih = (const float*)d_in[1];
    const float* W_hh = (const float*)d_in[2];
    const float* b_ih = (const float*)d_in[3];
    const float* b_hh = (const float*)d_in[4];
    const float* W_d  = (const float*)d_in[5];
    const float* b_d  = (const float*)d_in[6];
    float* out = (float*)d_out;

    dim3 grid(BATCH / 4);   // 512 blocks x 4 waves = 2048 waves (one per batch row)
    dim3 block(256);
    lstm_kernel<<<grid, block, 0, stream>>>(x, W_ih, W_hh, b_ih, b_hh, W_d, b_d, out);
}